// Round 5
// baseline (438.001 us; speedup 1.0000x reference)
//
#include <hip/hip_runtime.h>
#include <cstdint>
#include <cstddef>

#define NB   16
#define NC   256
#define NPIX 3136
#define NW   56
#define EPSV 1e-5f

// ws layout in dwords/floats
#define OFF_AB   0u        // Abf: 12 dtiles x 16 kchunks x 64 lanes x 4 dw = 49152
#define OFF_BNA  49152u    // [384] (BNB contiguous after)
#define OFF_BNB  49536u    // [384]
#define OFF_WT   49920u    // wtab: 32 chunks x 64 lanes x 4 dw = 8192
#define OFF_LC   58112u    // Lc[16][16][64] = 16384
#define OFF_Y    74496u    // Y[16][384][3136]; per-b dwords 0..32*NPIX = qb2 (uint2 bf16 pairs)

typedef short bf16x8 __attribute__((ext_vector_type(8)));
typedef float f32x4  __attribute__((ext_vector_type(4)));
typedef float f32x16 __attribute__((ext_vector_type(16)));

__device__ __forceinline__ uint32_t f2bf(float f) {
  uint32_t x = __float_as_uint(f);
  uint32_t r = x + 0x7fffu + ((x >> 16) & 1u);
  return r >> 16;
}

__device__ __forceinline__ float fetchW(const float* Wq, const float* Wk,
                                        const float* Wv, int m, int c) {
  if (m < 64)  return Wq[c * 64 + m];
  if (m < 128) return Wk[c * 64 + (m - 64)];
  return Wv[c * 256 + (m - 128)];
}

// ---------------- prep: bf16 A-fragments, BN coeffs, pos-w fragments, zero Lc -
__global__ void prep_kernel(const float* __restrict__ Wq, const float* __restrict__ Wk,
                            const float* __restrict__ Wv, const float* __restrict__ pos_w,
                            const float* __restrict__ gq, const float* __restrict__ bq,
                            const float* __restrict__ mq, const float* __restrict__ vq,
                            const float* __restrict__ gv, const float* __restrict__ bv,
                            const float* __restrict__ mv, const float* __restrict__ vv,
                            float* __restrict__ ws) {
  int d = blockIdx.x;    // 0..383
  int c = threadIdx.x;   // 0..255
  int i = d * 256 + c;
  // A fragment table for mfma_32x32x16_bf16
  if (i < 49152) {
    int dgt = i >> 12, rem = i & 4095;
    int kc = rem >> 8, rem2 = rem & 255;
    int lane = rem2 >> 2, dp = rem2 & 3;
    int m = dgt * 32 + (lane & 31);
    int k0 = kc * 16 + (lane >> 5) * 8 + dp * 2;
    float w0 = fetchW(Wq, Wk, Wv, m, k0);
    float w1 = fetchW(Wq, Wk, Wv, m, k0 + 1);
    ((uint32_t*)(ws + OFF_AB))[i] = f2bf(w0) | (f2bf(w1) << 16);
  }
  if (c == 0) {
    float sa, sb;
    if (d < 64)        { float inv = gq[d] / sqrtf(vq[d] + EPSV); sa = inv; sb = bq[d] - mq[d] * inv; }
    else if (d < 128)  { sa = 1.0f; sb = 0.0f; }
    else               { int j = d - 128; float inv = gv[j] / sqrtf(vv[j] + EPSV); sa = inv; sb = bv[j] - mv[j] * inv; }
    ws[OFF_BNA + d] = sa;
    ws[OFF_BNB + d] = sb;
  }
  // pos-w fragment table (16x16x32 path in pos_lambda)
  if (i < 8192) {
    int chunk = i >> 8, rem = i & 255, lane = rem >> 2, dp = rem & 3;
    int quad = lane >> 4, k = lane & 15;
    int u = chunk >> 3, t = chunk & 7;
    int dh = 2 * t + (quad >> 1);
    int dwb = (quad & 1) * 8 + dp * 2;
    float w0 = (dh < 15 && dwb     < 15) ? pos_w[k * 900 + u * 225 + dh * 15 + dwb]     : 0.0f;
    float w1 = (dh < 15 && dwb + 1 < 15) ? pos_w[k * 900 + u * 225 + dh * 15 + dwb + 1] : 0.0f;
    ((uint32_t*)(ws + OFF_WT))[i] = f2bf(w0) | (f2bf(w1) << 16);
  }
  if (d < 64) ws[OFF_LC + i] = 0.0f;
}

// ---------------- stage 1: QKV projection via MFMA 32x32x16 bf16 --------------
__launch_bounds__(256, 2)
__global__ void qkv_mfma(const float* __restrict__ x, const float* __restrict__ wsc,
                         float* __restrict__ Y) {
  __shared__ uint32_t X[64 * 128];   // 32 KB
  __shared__ float BNs[768];
  int tid = threadIdx.x;
  int n0 = blockIdx.x * 64, b = blockIdx.y;
  for (int i = tid; i < 768; i += 256) BNs[i] = wsc[OFF_BNA + i];
  const size_t xb = (size_t)b * NC * NPIX;
#pragma unroll
  for (int it = 0; it < 4; ++it) {
    int n2 = tid & 31;
    int cp4 = it * 8 + (tid >> 5);
    const float* xp = x + xb + (size_t)(cp4 * 8) * NPIX + n0 + n2 * 2;
    float2 ld[8];
#pragma unroll
    for (int j = 0; j < 8; ++j) ld[j] = *(const float2*)(xp + (size_t)j * NPIX);
    uint32_t e0, e1, e2, e3, o0, o1, o2, o3;
    e0 = f2bf(ld[0].x) | (f2bf(ld[1].x) << 16);
    e1 = f2bf(ld[2].x) | (f2bf(ld[3].x) << 16);
    e2 = f2bf(ld[4].x) | (f2bf(ld[5].x) << 16);
    e3 = f2bf(ld[6].x) | (f2bf(ld[7].x) << 16);
    o0 = f2bf(ld[0].y) | (f2bf(ld[1].y) << 16);
    o1 = f2bf(ld[2].y) | (f2bf(ld[3].y) << 16);
    o2 = f2bf(ld[4].y) | (f2bf(ld[5].y) << 16);
    o3 = f2bf(ld[6].y) | (f2bf(ld[7].y) << 16);
    int ne = 2 * n2, no = ne + 1;
    uint4 ve; ve.x = e0; ve.y = e1; ve.z = e2; ve.w = e3;
    uint4 vo; vo.x = o0; vo.y = o1; vo.z = o2; vo.w = o3;
    *(uint4*)(X + ne * 128 + ((cp4 ^ (ne & 31)) << 2)) = ve;
    *(uint4*)(X + no * 128 + ((cp4 ^ (no & 31)) << 2)) = vo;
  }
  __syncthreads();
  int lane = tid & 63, w = tid >> 6;
  int n31 = lane & 31, h5 = lane >> 5;
  f32x16 acc[3][2];
#pragma unroll
  for (int dt = 0; dt < 3; ++dt)
#pragma unroll
    for (int nt = 0; nt < 2; ++nt)
#pragma unroll
      for (int e = 0; e < 16; ++e) acc[dt][nt][e] = 0.0f;
  const uint4* AB = (const uint4*)(wsc + OFF_AB);
#pragma unroll 4
  for (int kc = 0; kc < 16; ++kc) {
    bf16x8 af[3];
#pragma unroll
    for (int dt = 0; dt < 3; ++dt) {
      union { uint4 q; bf16x8 v; } tmp;
      tmp.q = AB[(size_t)(((w * 3 + dt) * 16 + kc)) * 64 + lane];
      af[dt] = tmp.v;
    }
#pragma unroll
    for (int nt = 0; nt < 2; ++nt) {
      union { uint4 q; bf16x8 v; } bu;
      bu.q = *(const uint4*)(X + (nt * 32 + n31) * 128 + (((2 * kc + h5) ^ n31) << 2));
#pragma unroll
      for (int dt = 0; dt < 3; ++dt)
        acc[dt][nt] = __builtin_amdgcn_mfma_f32_32x32x16_bf16(af[dt], bu.v, acc[dt][nt], 0, 0, 0);
    }
  }
#pragma unroll
  for (int dt = 0; dt < 3; ++dt) {
    int dgt = w * 3 + dt;
    float sa[16], sb[16];
#pragma unroll
    for (int g = 0; g < 4; ++g) {
      *(float4*)(sa + g * 4) = *(const float4*)(BNs + dgt * 32 + g * 8 + h5 * 4);
      *(float4*)(sb + g * 4) = *(const float4*)(BNs + 384 + dgt * 32 + g * 8 + h5 * 4);
    }
#pragma unroll
    for (int nt = 0; nt < 2; ++nt) {
      int pix = n0 + nt * 32 + n31;
      if (dgt < 2) {
        uint2* qb2 = (uint2*)(Y + (size_t)b * 384 * NPIX);
#pragma unroll
        for (int g = 0; g < 4; ++g) {
          float y0 = fmaf(acc[dt][nt][4 * g + 0], sa[4 * g + 0], sb[4 * g + 0]);
          float y1 = fmaf(acc[dt][nt][4 * g + 1], sa[4 * g + 1], sb[4 * g + 1]);
          float y2 = fmaf(acc[dt][nt][4 * g + 2], sa[4 * g + 2], sb[4 * g + 2]);
          float y3 = fmaf(acc[dt][nt][4 * g + 3], sa[4 * g + 3], sb[4 * g + 3]);
          uint2 val;
          val.x = f2bf(y0) | (f2bf(y1) << 16);
          val.y = f2bf(y2) | (f2bf(y3) << 16);
          qb2[(size_t)(dgt * 8 + 2 * g + h5) * NPIX + pix] = val;
        }
      } else {
#pragma unroll
        for (int g = 0; g < 4; ++g)
#pragma unroll
          for (int ki = 0; ki < 4; ++ki) {
            int d = dgt * 32 + 8 * g + 4 * h5 + ki;
            Y[((size_t)b * 384 + d) * NPIX + pix] =
                fmaf(acc[dt][nt][4 * g + ki], sa[4 * g + ki], sb[4 * g + ki]);
          }
      }
    }
  }
}

// ---------------- stage 2: softmax over positions (2-pass, no max: |k|<~5) ----
__global__ void softmax_k(float* __restrict__ Y) {
  int row = blockIdx.x;
  int b = row >> 6, r = row & 63;
  float* p = Y + ((size_t)b * 384 + 64 + r) * NPIX;
  int t = threadIdx.x;
  __shared__ float red[4];
  float s = 0.0f;
  for (int n = t; n < NPIX; n += 256) s += __expf(p[n]);
#pragma unroll
  for (int off = 32; off; off >>= 1) s += __shfl_xor(s, off, 64);
  if ((t & 63) == 0) red[t >> 6] = s;
  __syncthreads();
  float inv = 1.0f / (red[0] + red[1] + red[2] + red[3]);
  for (int n = t; n < NPIX; n += 256) p[n] = __expf(p[n]) * inv;
}

// ---------------- stage 3: Lc via LDS-tiled outer product ---------------------
// grid (8 ntile, 4 u, 16 b); 256 thr = 4 waves; lane = k(0..15) + 16*vg(0..3).
// Each lane accumulates Lc[k][vg*16 .. vg*16+15] over its block's n-range.
#define LCN   392
#define LCSUB 56
__launch_bounds__(256)
__global__ void lc_kernel(const float* __restrict__ Y, float* __restrict__ ws) {
  __shared__ float ksT[LCSUB * 17];   // [n][k], stride 17
  __shared__ float vsT[LCSUB * 68];   // [n][v], stride 68 (float4-aligned)
  int ntile = blockIdx.x, u = blockIdx.y, b = blockIdx.z;
  int n0 = ntile * LCN;
  int t = threadIdx.x;
  const float* krows = Y + ((size_t)b * 384 + 64 + u * 16) * NPIX;
  const float* vrows = Y + ((size_t)b * 384 + 128 + u * 64) * NPIX;
  int lane = t & 63, w = t >> 6;
  int k = lane & 15, vg = lane >> 4;
  float acc[16];
#pragma unroll
  for (int i = 0; i < 16; ++i) acc[i] = 0.0f;
  for (int sc = 0; sc < 7; ++sc) {
    int nb = n0 + sc * LCSUB;
    __syncthreads();
    if (t < 224) {
      int kk = t / 14, c4 = (t % 14) * 4;
      float4 f = *(const float4*)(krows + (size_t)kk * NPIX + nb + c4);
      ksT[(c4 + 0) * 17 + kk] = f.x; ksT[(c4 + 1) * 17 + kk] = f.y;
      ksT[(c4 + 2) * 17 + kk] = f.z; ksT[(c4 + 3) * 17 + kk] = f.w;
    }
    for (int wu = t; wu < 896; wu += 256) {
      int vv = wu / 14, c4 = (wu % 14) * 4;
      float4 f = *(const float4*)(vrows + (size_t)vv * NPIX + nb + c4);
      vsT[(c4 + 0) * 68 + vv] = f.x; vsT[(c4 + 1) * 68 + vv] = f.y;
      vsT[(c4 + 2) * 68 + vv] = f.z; vsT[(c4 + 3) * 68 + vv] = f.w;
    }
    __syncthreads();
#pragma unroll
    for (int ni = 0; ni < 14; ++ni) {
      int n = ni * 4 + w;
      float kv = ksT[n * 17 + k];
      const float4* vr = (const float4*)(vsT + n * 68 + vg * 16);
      float4 a = vr[0], bq = vr[1], cq = vr[2], dq = vr[3];
      acc[0]  = fmaf(kv, a.x,  acc[0]);  acc[1]  = fmaf(kv, a.y,  acc[1]);
      acc[2]  = fmaf(kv, a.z,  acc[2]);  acc[3]  = fmaf(kv, a.w,  acc[3]);
      acc[4]  = fmaf(kv, bq.x, acc[4]);  acc[5]  = fmaf(kv, bq.y, acc[5]);
      acc[6]  = fmaf(kv, bq.z, acc[6]);  acc[7]  = fmaf(kv, bq.w, acc[7]);
      acc[8]  = fmaf(kv, cq.x, acc[8]);  acc[9]  = fmaf(kv, cq.y, acc[9]);
      acc[10] = fmaf(kv, cq.z, acc[10]); acc[11] = fmaf(kv, cq.w, acc[11]);
      acc[12] = fmaf(kv, dq.x, acc[12]); acc[13] = fmaf(kv, dq.y, acc[13]);
      acc[14] = fmaf(kv, dq.z, acc[14]); acc[15] = fmaf(kv, dq.w, acc[15]);
    }
  }
  float* Lc = ws + OFF_LC;
#pragma unroll
  for (int i = 0; i < 16; ++i)
    atomicAdd(&Lc[(b * 16 + k) * 64 + vg * 16 + i], acc[i]);
}

// ---------------- stage 4: MFMA position conv + fused output contraction ------
#define ROWS   29
#define RSTR2  74
#define UPITCH2 2146   // ROWS * RSTR2
#define LDSW2  8584    // 4 * UPITCH2

__launch_bounds__(512, 4)
__global__ void pos_lambda_mfma(const float* __restrict__ Y, const float* __restrict__ wsc,
                                const float* __restrict__ pos_b, float* __restrict__ out) {
  __shared__ uint32_t S[LDSW2];
  int v = blockIdx.x, b = blockIdx.y, band = blockIdx.z;
  int rb = band * 14;
  int tid = threadIdx.x;
  // ---- stage padded v planes: thread = (row 0..115, quarter 0..3) ----
  {
    int row = tid >> 2, qt = tid & 3;
    if (row < 116) {
      int u = row / 29, prow = row - u * 29;
      int gr = rb + prow - 7;
      uint32_t* dst = S + u * UPITCH2 + prow * RSTR2 + qt * 19;
      int p0 = qt * 19;
      float e[20];
      if (gr >= 0 && gr < NW) {
        const float* vp = Y + ((size_t)(b * 384 + 128 + u * 64 + v)) * NPIX + gr * NW;
#pragma unroll
        for (int j = 0; j < 20; ++j) {
          int g = p0 + j - 7;
          e[j] = (g >= 0 && g < NW) ? vp[g] : 0.0f;
        }
      } else {
#pragma unroll
        for (int j = 0; j < 20; ++j) e[j] = 0.0f;
      }
#pragma unroll
      for (int j = 0; j < 19; ++j) {
        if (p0 + j < 74) dst[j] = f2bf(e[j]) | (f2bf(e[j + 1]) << 16);
      }
    }
  }
  __syncthreads();
  int lane = tid & 63, wid = tid >> 6;
  int quad = lane >> 4, n = lane & 15;
  int dhp = quad >> 1;
  int ct = wid & 3, p = wid >> 2;
  int cb = (ct == 3) ? 40 : ct * 16;
  int sb = cb + n + (quad & 1) * 8;
  int abase = (p + dhp) * RSTR2 + sb;
  const uint4* wt = (const uint4*)(wsc + OFF_WT);
  f32x4 acc[7];
#pragma unroll
  for (int q = 0; q < 7; ++q) acc[q] = (f32x4){0.f, 0.f, 0.f, 0.f};
#pragma unroll 1
  for (int u = 0; u < 4; ++u) {
    bf16x8 wf[8];
#pragma unroll
    for (int t = 0; t < 8; ++t) {
      union { uint4 q; bf16x8 v; } tmp;
      tmp.q = wt[(u * 8 + t) * 64 + lane];
      wf[t] = tmp.v;
    }
    int au = u * UPITCH2 + abase;
#pragma unroll
    for (int PP = 0; PP < 14; ++PP) {
      int a = au + PP * (2 * RSTR2);
      union { uint32_t u4[4]; bf16x8 v8; } bu;
      bu.u4[0] = S[a];     bu.u4[1] = S[a + 2];
      bu.u4[2] = S[a + 4]; bu.u4[3] = S[a + 6];
#pragma unroll
      for (int t = 0; t < 8; ++t) {
        int q = PP - t;
        if (q >= 0 && q < 7)
          acc[q] = __builtin_amdgcn_mfma_f32_16x16x32_bf16(wf[t], bu.v8, acc[q], 0, 0, 0);
      }
    }
  }
  float lcq[4];
#pragma unroll
  for (int r = 0; r < 4; ++r) {
    int k = quad * 4 + r;
    lcq[r] = wsc[OFF_LC + (b * 16 + k) * 64 + v] + pos_b[k];
  }
  const uint2* qb2 = (const uint2*)(Y + (size_t)b * 384 * NPIX);
#pragma unroll
  for (int q = 0; q < 7; ++q) {
    int rr = rb + p + 2 * q;
    int pix = rr * NW + cb + n;
    float m0 = acc[q][0] + lcq[0], m1 = acc[q][1] + lcq[1];
    float m2 = acc[q][2] + lcq[2], m3 = acc[q][3] + lcq[3];
    // lane computes partials for h = quad ^ j; xor-butterfly completes h=quad
    float pp[4];
#pragma unroll
    for (int j = 0; j < 4; ++j) {
      int h = quad ^ j;
      uint2 qd = qb2[(h * 4 + quad) * NPIX + pix];
      float q0 = __uint_as_float(qd.x << 16);
      float q1 = __uint_as_float(qd.x & 0xffff0000u);
      float q2 = __uint_as_float(qd.y << 16);
      float q3 = __uint_as_float(qd.y & 0xffff0000u);
      pp[j] = fmaf(q0, m0, fmaf(q1, m1, fmaf(q2, m2, q3 * m3)));
    }
    float t0 = pp[0] + __shfl_xor(pp[1], 16);
    float t2 = pp[2] + __shfl_xor(pp[3], 16);
    float y  = t0 + __shfl_xor(t2, 32);
    out[((size_t)(b * 256 + quad * 64 + v)) * NPIX + pix] = y;
  }
}

extern "C" void kernel_launch(void* const* d_in, const int* in_sizes, int n_in,
                              void* d_out, int out_size, void* d_ws, size_t ws_size,
                              hipStream_t stream) {
  const float* x     = (const float*)d_in[0];
  const float* Wq    = (const float*)d_in[1];
  const float* Wk    = (const float*)d_in[2];
  const float* Wv    = (const float*)d_in[3];
  const float* pos_w = (const float*)d_in[4];
  const float* pos_b = (const float*)d_in[5];
  const float* gq    = (const float*)d_in[6];
  const float* bq    = (const float*)d_in[7];
  const float* mq    = (const float*)d_in[8];
  const float* vq    = (const float*)d_in[9];
  const float* gv    = (const float*)d_in[10];
  const float* bv    = (const float*)d_in[11];
  const float* mv    = (const float*)d_in[12];
  const float* vv    = (const float*)d_in[13];
  float* ws  = (float*)d_ws;
  float* out = (float*)d_out;
  float* Y   = ws + OFF_Y;

  prep_kernel<<<dim3(384), 256, 0, stream>>>(Wq, Wk, Wv, pos_w, gq, bq, mq, vq,
                                             gv, bv, mv, vv, ws);
  qkv_mfma<<<dim3(49, 16), 256, 0, stream>>>(x, ws, Y);
  softmax_k<<<dim3(1024), 256, 0, stream>>>(Y);
  lc_kernel<<<dim3(8, 4, 16), 256, 0, stream>>>(Y, ws);
  pos_lambda_mfma<<<dim3(64, 16, 4), 512, 0, stream>>>(Y, ws, pos_b, out);
}

// Round 6
// 274.899 us; speedup vs baseline: 1.5933x; 1.5933x over previous
//
#include <hip/hip_runtime.h>
#include <cstdint>
#include <cstddef>

#define NB   16
#define NC   256
#define NPIX 3136
#define NW   56
#define EPSV 1e-5f

// ws layout in dwords/floats
#define OFF_AB   0u        // Abf: 12 dtiles x 16 kchunks x 64 lanes x 4 dw = 49152
#define OFF_BNA  49152u    // [384]
#define OFF_BNB  49536u    // [384]
#define OFF_WT   49920u    // wtab: 32 chunks x 64 lanes x 4 dw = 8192
#define OFF_KS   58112u    // S[b][u][k] = 1024 (exp row sums)
#define OFF_LC   59136u    // Lc[16][16][64] = 16384
#define OFF_Y    75520u    // Y[16][384][3136]; per-b: dw [0,32N) qb2; [32N,64N) lc partials; k,v fp32
// per-b partials live at Y + b*384*NPIX + 32*NPIX + slot*1024, slot = u*16 + ks*4 + w (64 slots)

typedef short bf16x8 __attribute__((ext_vector_type(8)));
typedef float f32x4  __attribute__((ext_vector_type(4)));
typedef float f32x16 __attribute__((ext_vector_type(16)));

__device__ __forceinline__ uint32_t f2bf(float f) {
  uint32_t x = __float_as_uint(f);
  uint32_t r = x + 0x7fffu + ((x >> 16) & 1u);
  return r >> 16;
}

__device__ __forceinline__ float fetchW(const float* Wq, const float* Wk,
                                        const float* Wv, int m, int c) {
  if (m < 64)  return Wq[c * 64 + m];
  if (m < 128) return Wk[c * 64 + (m - 64)];
  return Wv[c * 256 + (m - 128)];
}

// ---------------- prep: bf16 A-fragments, BN coeffs, pos-w fragments, zero S --
__global__ void prep_kernel(const float* __restrict__ Wq, const float* __restrict__ Wk,
                            const float* __restrict__ Wv, const float* __restrict__ pos_w,
                            const float* __restrict__ gq, const float* __restrict__ bq,
                            const float* __restrict__ mq, const float* __restrict__ vq,
                            const float* __restrict__ gv, const float* __restrict__ bv,
                            const float* __restrict__ mv, const float* __restrict__ vv,
                            float* __restrict__ ws) {
  int d = blockIdx.x;    // 0..383
  int c = threadIdx.x;   // 0..255
  int i = d * 256 + c;
  if (i < 49152) {
    int dgt = i >> 12, rem = i & 4095;
    int kc = rem >> 8, rem2 = rem & 255;
    int lane = rem2 >> 2, dp = rem2 & 3;
    int m = dgt * 32 + (lane & 31);
    int k0 = kc * 16 + (lane >> 5) * 8 + dp * 2;
    float w0 = fetchW(Wq, Wk, Wv, m, k0);
    float w1 = fetchW(Wq, Wk, Wv, m, k0 + 1);
    ((uint32_t*)(ws + OFF_AB))[i] = f2bf(w0) | (f2bf(w1) << 16);
  }
  if (c == 0) {
    float sa, sb;
    if (d < 64)        { float inv = gq[d] / sqrtf(vq[d] + EPSV); sa = inv; sb = bq[d] - mq[d] * inv; }
    else if (d < 128)  { sa = 1.0f; sb = 0.0f; }
    else               { int j = d - 128; float inv = gv[j] / sqrtf(vv[j] + EPSV); sa = inv; sb = bv[j] - mv[j] * inv; }
    ws[OFF_BNA + d] = sa;
    ws[OFF_BNB + d] = sb;
  }
  if (i < 8192) {
    int chunk = i >> 8, rem = i & 255, lane = rem >> 2, dp = rem & 3;
    int quad = lane >> 4, k = lane & 15;
    int u = chunk >> 3, t = chunk & 7;
    int dh = 2 * t + (quad >> 1);
    int dwb = (quad & 1) * 8 + dp * 2;
    float w0 = (dh < 15 && dwb     < 15) ? pos_w[k * 900 + u * 225 + dh * 15 + dwb]     : 0.0f;
    float w1 = (dh < 15 && dwb + 1 < 15) ? pos_w[k * 900 + u * 225 + dh * 15 + dwb + 1] : 0.0f;
    ((uint32_t*)(ws + OFF_WT))[i] = f2bf(w0) | (f2bf(w1) << 16);
  }
  if (i < 1024) ws[OFF_KS + i] = 0.0f;
}

// ---------------- stage 1: QKV projection via MFMA 32x32x16 bf16 --------------
__launch_bounds__(256, 2)
__global__ void qkv_mfma(const float* __restrict__ x, const float* __restrict__ wsc,
                         float* __restrict__ Y) {
  __shared__ uint32_t X[64 * 128];   // 32 KB
  __shared__ float BNs[768];
  int tid = threadIdx.x;
  int n0 = blockIdx.x * 64, b = blockIdx.y;
  for (int i = tid; i < 768; i += 256) BNs[i] = wsc[OFF_BNA + i];
  const size_t xb = (size_t)b * NC * NPIX;
#pragma unroll
  for (int it = 0; it < 4; ++it) {
    int n2 = tid & 31;
    int cp4 = it * 8 + (tid >> 5);
    const float* xp = x + xb + (size_t)(cp4 * 8) * NPIX + n0 + n2 * 2;
    float2 ld[8];
#pragma unroll
    for (int j = 0; j < 8; ++j) ld[j] = *(const float2*)(xp + (size_t)j * NPIX);
    uint32_t e0, e1, e2, e3, o0, o1, o2, o3;
    e0 = f2bf(ld[0].x) | (f2bf(ld[1].x) << 16);
    e1 = f2bf(ld[2].x) | (f2bf(ld[3].x) << 16);
    e2 = f2bf(ld[4].x) | (f2bf(ld[5].x) << 16);
    e3 = f2bf(ld[6].x) | (f2bf(ld[7].x) << 16);
    o0 = f2bf(ld[0].y) | (f2bf(ld[1].y) << 16);
    o1 = f2bf(ld[2].y) | (f2bf(ld[3].y) << 16);
    o2 = f2bf(ld[4].y) | (f2bf(ld[5].y) << 16);
    o3 = f2bf(ld[6].y) | (f2bf(ld[7].y) << 16);
    int ne = 2 * n2, no = ne + 1;
    uint4 ve; ve.x = e0; ve.y = e1; ve.z = e2; ve.w = e3;
    uint4 vo; vo.x = o0; vo.y = o1; vo.z = o2; vo.w = o3;
    *(uint4*)(X + ne * 128 + ((cp4 ^ (ne & 31)) << 2)) = ve;
    *(uint4*)(X + no * 128 + ((cp4 ^ (no & 31)) << 2)) = vo;
  }
  __syncthreads();
  int lane = tid & 63, w = tid >> 6;
  int n31 = lane & 31, h5 = lane >> 5;
  f32x16 acc[3][2];
#pragma unroll
  for (int dt = 0; dt < 3; ++dt)
#pragma unroll
    for (int nt = 0; nt < 2; ++nt)
#pragma unroll
      for (int e = 0; e < 16; ++e) acc[dt][nt][e] = 0.0f;
  const uint4* AB = (const uint4*)(wsc + OFF_AB);
#pragma unroll 4
  for (int kc = 0; kc < 16; ++kc) {
    bf16x8 af[3];
#pragma unroll
    for (int dt = 0; dt < 3; ++dt) {
      union { uint4 q; bf16x8 v; } tmp;
      tmp.q = AB[(size_t)(((w * 3 + dt) * 16 + kc)) * 64 + lane];
      af[dt] = tmp.v;
    }
#pragma unroll
    for (int nt = 0; nt < 2; ++nt) {
      union { uint4 q; bf16x8 v; } bu;
      bu.q = *(const uint4*)(X + (nt * 32 + n31) * 128 + (((2 * kc + h5) ^ n31) << 2));
#pragma unroll
      for (int dt = 0; dt < 3; ++dt)
        acc[dt][nt] = __builtin_amdgcn_mfma_f32_32x32x16_bf16(af[dt], bu.v, acc[dt][nt], 0, 0, 0);
    }
  }
#pragma unroll
  for (int dt = 0; dt < 3; ++dt) {
    int dgt = w * 3 + dt;
    float sa[16], sb[16];
#pragma unroll
    for (int g = 0; g < 4; ++g) {
      *(float4*)(sa + g * 4) = *(const float4*)(BNs + dgt * 32 + g * 8 + h5 * 4);
      *(float4*)(sb + g * 4) = *(const float4*)(BNs + 384 + dgt * 32 + g * 8 + h5 * 4);
    }
#pragma unroll
    for (int nt = 0; nt < 2; ++nt) {
      int pix = n0 + nt * 32 + n31;
      if (dgt < 2) {
        uint2* qb2 = (uint2*)(Y + (size_t)b * 384 * NPIX);
#pragma unroll
        for (int g = 0; g < 4; ++g) {
          float y0 = fmaf(acc[dt][nt][4 * g + 0], sa[4 * g + 0], sb[4 * g + 0]);
          float y1 = fmaf(acc[dt][nt][4 * g + 1], sa[4 * g + 1], sb[4 * g + 1]);
          float y2 = fmaf(acc[dt][nt][4 * g + 2], sa[4 * g + 2], sb[4 * g + 2]);
          float y3 = fmaf(acc[dt][nt][4 * g + 3], sa[4 * g + 3], sb[4 * g + 3]);
          uint2 val;
          val.x = f2bf(y0) | (f2bf(y1) << 16);
          val.y = f2bf(y2) | (f2bf(y3) << 16);
          qb2[(size_t)(dgt * 8 + 2 * g + h5) * NPIX + pix] = val;
        }
      } else {
#pragma unroll
        for (int g = 0; g < 4; ++g)
#pragma unroll
          for (int ki = 0; ki < 4; ++ki) {
            int d = dgt * 32 + 8 * g + 4 * h5 + ki;
            Y[((size_t)b * 384 + d) * NPIX + pix] =
                fmaf(acc[dt][nt][4 * g + ki], sa[4 * g + ki], sb[4 * g + ki]);
          }
      }
    }
  }
}

// ---------------- stage 2: Lc partials via MFMA, exp(k) inline ----------------
// C[v][k] = sum_n v[v,n]*exp(k[k,n]) per (b,u). A-frag: 8 consec n from v-row;
// B-frag: 8 consec n from k-row (exp'd). Row sums S via shfl + 16 atomics/wave.
// grid (4 ks, 4 u, 16 b), 256 thr. Wave slot = ks*4+w handles chunks slot+16i.
__launch_bounds__(256)
__global__ void lc_mfma(float* __restrict__ Y, float* __restrict__ ws) {
  int ks = blockIdx.x, u = blockIdx.y, b = blockIdx.z;
  int tid = threadIdx.x;
  int lane = tid & 63, w = tid >> 6;
  int col = lane & 15, quad = lane >> 4;
  int slot = ks * 4 + w;
  const float* krow  = Y + ((size_t)(b * 384 + 64 + u * 16 + col)) * NPIX;
  const float* vbase = Y + ((size_t)(b * 384 + 128 + u * 64 + col)) * NPIX;
  f32x4 acc[4];
#pragma unroll
  for (int vt = 0; vt < 4; ++vt) acc[vt] = (f32x4){0.f, 0.f, 0.f, 0.f};
  float ssum = 0.0f;
  for (int c = slot; c < 98; c += 16) {
    int n0 = c * 32 + quad * 8;
    float4 k0 = *(const float4*)(krow + n0);
    float4 k1 = *(const float4*)(krow + n0 + 4);
    float e0 = __expf(k0.x), e1 = __expf(k0.y), e2 = __expf(k0.z), e3 = __expf(k0.w);
    float e4 = __expf(k1.x), e5 = __expf(k1.y), e6 = __expf(k1.z), e7 = __expf(k1.w);
    ssum += (e0 + e1 + e2 + e3) + (e4 + e5 + e6 + e7);
    union { uint32_t d[4]; bf16x8 v; } kb;
    kb.d[0] = f2bf(e0) | (f2bf(e1) << 16);
    kb.d[1] = f2bf(e2) | (f2bf(e3) << 16);
    kb.d[2] = f2bf(e4) | (f2bf(e5) << 16);
    kb.d[3] = f2bf(e6) | (f2bf(e7) << 16);
#pragma unroll
    for (int vt = 0; vt < 4; ++vt) {
      const float* vp = vbase + (size_t)(vt * 16) * NPIX + n0;
      float4 v0 = *(const float4*)(vp);
      float4 v1 = *(const float4*)(vp + 4);
      union { uint32_t d[4]; bf16x8 v; } vb;
      vb.d[0] = f2bf(v0.x) | (f2bf(v0.y) << 16);
      vb.d[1] = f2bf(v0.z) | (f2bf(v0.w) << 16);
      vb.d[2] = f2bf(v1.x) | (f2bf(v1.y) << 16);
      vb.d[3] = f2bf(v1.z) | (f2bf(v1.w) << 16);
      acc[vt] = __builtin_amdgcn_mfma_f32_16x16x32_bf16(vb.v, kb.v, acc[vt], 0, 0, 0);
    }
  }
  // S[b][u][col] += sum over quads of ssum
  ssum += __shfl_xor(ssum, 16);
  ssum += __shfl_xor(ssum, 32);
  if (lane < 16) atomicAdd(&ws[OFF_KS + b * 64 + u * 16 + col], ssum);
  // store partial tile: idx = v*16+k, v = vt*16 + quad*4 + r, k = col
  float* P = Y + (size_t)b * 384 * NPIX + 32 * NPIX + (size_t)(u * 16 + slot) * 1024;
#pragma unroll
  for (int vt = 0; vt < 4; ++vt)
#pragma unroll
    for (int r = 0; r < 4; ++r)
      P[vt * 256 + quad * 64 + r * 16 + col] = acc[vt][r];
}

// ---------------- stage 3: reduce partials -> Lc (scaled by 1/S) --------------
// grid (4 i, 16 b), 256 thr; thread handles idx = i*256 + t.
__global__ void lc_reduce(const float* __restrict__ Y, float* __restrict__ ws) {
  int i = blockIdx.x, b = blockIdx.y;
  int t = threadIdx.x;
  __shared__ float invS[64];
  if (t < 64) invS[t] = 1.0f / ws[OFF_KS + b * 64 + t];
  __syncthreads();
  int idx = i * 256 + t;
  int k = idx & 15, v = idx >> 4;
  const float* P = Y + (size_t)b * 384 * NPIX + 32 * NPIX;
  float tot = 0.0f;
#pragma unroll
  for (int u = 0; u < 4; ++u) {
    float su = 0.0f;
#pragma unroll
    for (int s = 0; s < 16; ++s) su += P[(size_t)(u * 16 + s) * 1024 + idx];
    tot += su * invS[u * 16 + k];
  }
  ws[OFF_LC + (b * 16 + k) * 64 + v] = tot;
}

// ---------------- stage 4: MFMA position conv + fused output contraction ------
#define ROWS   29
#define RSTR2  74
#define UPITCH2 2146   // ROWS * RSTR2
#define LDSW2  8584    // 4 * UPITCH2

__launch_bounds__(512, 4)
__global__ void pos_lambda_mfma(const float* __restrict__ Y, const float* __restrict__ wsc,
                                const float* __restrict__ pos_b, float* __restrict__ out) {
  __shared__ uint32_t S[LDSW2];
  int v = blockIdx.x, b = blockIdx.y, band = blockIdx.z;
  int rb = band * 14;
  int tid = threadIdx.x;
  for (int i = tid; i < LDSW2; i += 512) {
    int u = i / UPITCH2; int rem = i - u * UPITCH2;
    int prow = rem / RSTR2; int pos = rem - prow * RSTR2;
    int gr = rb + prow - 7;
    float f0 = 0.0f, f1 = 0.0f;
    if (gr >= 0 && gr < NW && pos < 72) {
      const float* vp = Y + ((size_t)(b * 384 + 128 + u * 64 + v)) * NPIX + gr * NW;
      int g0 = pos - 7, g1 = pos - 6;
      if (g0 >= 0 && g0 < NW) f0 = vp[g0];
      if (g1 >= 0 && g1 < NW) f1 = vp[g1];
    }
    S[i] = f2bf(f0) | (f2bf(f1) << 16);
  }
  __syncthreads();
  int lane = tid & 63, wid = tid >> 6;
  int quad = lane >> 4, n = lane & 15;
  int dhp = quad >> 1;
  int ct = wid & 3, p = wid >> 2;
  int cb = (ct == 3) ? 40 : ct * 16;
  int sb = cb + n + (quad & 1) * 8;
  int abase = (p + dhp) * RSTR2 + sb;
  const uint4* wt = (const uint4*)(wsc + OFF_WT);
  f32x4 acc[7];
#pragma unroll
  for (int q = 0; q < 7; ++q) acc[q] = (f32x4){0.f, 0.f, 0.f, 0.f};
#pragma unroll 1
  for (int u = 0; u < 4; ++u) {
    bf16x8 wf[8];
#pragma unroll
    for (int t = 0; t < 8; ++t) {
      union { uint4 q; bf16x8 v; } tmp;
      tmp.q = wt[(u * 8 + t) * 64 + lane];
      wf[t] = tmp.v;
    }
    int au = u * UPITCH2 + abase;
#pragma unroll
    for (int PP = 0; PP < 14; ++PP) {
      int a = au + PP * (2 * RSTR2);
      union { uint32_t u4[4]; bf16x8 v8; } bu;
      bu.u4[0] = S[a];     bu.u4[1] = S[a + 2];
      bu.u4[2] = S[a + 4]; bu.u4[3] = S[a + 6];
#pragma unroll
      for (int t = 0; t < 8; ++t) {
        int q = PP - t;
        if (q >= 0 && q < 7)
          acc[q] = __builtin_amdgcn_mfma_f32_16x16x32_bf16(wf[t], bu.v8, acc[q], 0, 0, 0);
      }
    }
  }
  float lcq[4];
#pragma unroll
  for (int r = 0; r < 4; ++r) {
    int k = quad * 4 + r;
    lcq[r] = wsc[OFF_LC + (b * 16 + k) * 64 + v] + pos_b[k];
  }
  const uint2* qb2 = (const uint2*)(Y + (size_t)b * 384 * NPIX);
#pragma unroll
  for (int q = 0; q < 7; ++q) {
    int rr = rb + p + 2 * q;
    int pix = rr * NW + cb + n;
    float m0 = acc[q][0] + lcq[0], m1 = acc[q][1] + lcq[1];
    float m2 = acc[q][2] + lcq[2], m3 = acc[q][3] + lcq[3];
    float pp[4];
#pragma unroll
    for (int j = 0; j < 4; ++j) {
      int h = quad ^ j;
      uint2 qd = qb2[(h * 4 + quad) * NPIX + pix];
      float q0 = __uint_as_float(qd.x << 16);
      float q1 = __uint_as_float(qd.x & 0xffff0000u);
      float q2 = __uint_as_float(qd.y << 16);
      float q3 = __uint_as_float(qd.y & 0xffff0000u);
      pp[j] = fmaf(q0, m0, fmaf(q1, m1, fmaf(q2, m2, q3 * m3)));
    }
    float t0 = pp[0] + __shfl_xor(pp[1], 16);
    float t2 = pp[2] + __shfl_xor(pp[3], 16);
    float y  = t0 + __shfl_xor(t2, 32);
    out[((size_t)(b * 256 + quad * 64 + v)) * NPIX + pix] = y;
  }
}

extern "C" void kernel_launch(void* const* d_in, const int* in_sizes, int n_in,
                              void* d_out, int out_size, void* d_ws, size_t ws_size,
                              hipStream_t stream) {
  const float* x     = (const float*)d_in[0];
  const float* Wq    = (const float*)d_in[1];
  const float* Wk    = (const float*)d_in[2];
  const float* Wv    = (const float*)d_in[3];
  const float* pos_w = (const float*)d_in[4];
  const float* pos_b = (const float*)d_in[5];
  const float* gq    = (const float*)d_in[6];
  const float* bq    = (const float*)d_in[7];
  const float* mq    = (const float*)d_in[8];
  const float* vq    = (const float*)d_in[9];
  const float* gv    = (const float*)d_in[10];
  const float* bv    = (const float*)d_in[11];
  const float* mv    = (const float*)d_in[12];
  const float* vv    = (const float*)d_in[13];
  float* ws  = (float*)d_ws;
  float* out = (float*)d_out;
  float* Y   = ws + OFF_Y;

  prep_kernel<<<dim3(384), 256, 0, stream>>>(Wq, Wk, Wv, pos_w, gq, bq, mq, vq,
                                             gv, bv, mv, vv, ws);
  qkv_mfma<<<dim3(49, 16), 256, 0, stream>>>(x, ws, Y);
  lc_mfma<<<dim3(4, 4, 16), 256, 0, stream>>>(Y, ws);
  lc_reduce<<<dim3(4, 16), 256, 0, stream>>>(Y, ws);
  pos_lambda_mfma<<<dim3(64, 16, 4), 512, 0, stream>>>(Y, ws, pos_b, out);
}

// Round 7
// 269.592 us; speedup vs baseline: 1.6247x; 1.0197x over previous
//
#include <hip/hip_runtime.h>
#include <cstdint>
#include <cstddef>

#define NB   16
#define NC   256
#define NPIX 3136
#define NW   56
#define EPSV 1e-5f

// ws layout in dwords/floats
#define OFF_AB   0u        // Abf: 12 dtiles x 16 kchunks x 64 lanes x 4 dw = 49152
#define OFF_BNA  49152u    // [384]
#define OFF_BNB  49536u    // [384]
#define OFF_WT   49920u    // wtab: 32 chunks x 64 lanes x 4 dw = 8192
#define OFF_KS   58112u    // S[b][u][k] = 1024 (exp row sums)
#define OFF_LC   59136u    // Lc[16][16][64] = 16384
#define OFF_Y    75520u    // Y[16][384][3136]; per-b: dw [0,32N) qb2; [32N,64N) lc partials; k,v fp32
// per-b partials at Y + b*384*NPIX + 32*NPIX + slot*1024, slot = u*16 + bx (64 slots)

typedef short bf16x8 __attribute__((ext_vector_type(8)));
typedef float f32x4  __attribute__((ext_vector_type(4)));
typedef float f32x16 __attribute__((ext_vector_type(16)));

__device__ __forceinline__ uint32_t f2bf(float f) {
  uint32_t x = __float_as_uint(f);
  uint32_t r = x + 0x7fffu + ((x >> 16) & 1u);
  return r >> 16;
}
// truncating bf16 pair pack: 3 VALU vs ~9 for round-nearest
__device__ __forceinline__ uint32_t pk_trunc(float a, float b) {
  return (__float_as_uint(a) >> 16) | (__float_as_uint(b) & 0xffff0000u);
}

__device__ __forceinline__ float fetchW(const float* Wq, const float* Wk,
                                        const float* Wv, int m, int c) {
  if (m < 64)  return Wq[c * 64 + m];
  if (m < 128) return Wk[c * 64 + (m - 64)];
  return Wv[c * 256 + (m - 128)];
}

// ---------------- prep: bf16 A-fragments, BN coeffs, pos-w fragments, zero S --
__global__ void prep_kernel(const float* __restrict__ Wq, const float* __restrict__ Wk,
                            const float* __restrict__ Wv, const float* __restrict__ pos_w,
                            const float* __restrict__ gq, const float* __restrict__ bq,
                            const float* __restrict__ mq, const float* __restrict__ vq,
                            const float* __restrict__ gv, const float* __restrict__ bv,
                            const float* __restrict__ mv, const float* __restrict__ vv,
                            float* __restrict__ ws) {
  int d = blockIdx.x;    // 0..383
  int c = threadIdx.x;   // 0..255
  int i = d * 256 + c;
  if (i < 49152) {
    int dgt = i >> 12, rem = i & 4095;
    int kc = rem >> 8, rem2 = rem & 255;
    int lane = rem2 >> 2, dp = rem2 & 3;
    int m = dgt * 32 + (lane & 31);
    int k0 = kc * 16 + (lane >> 5) * 8 + dp * 2;
    float w0 = fetchW(Wq, Wk, Wv, m, k0);
    float w1 = fetchW(Wq, Wk, Wv, m, k0 + 1);
    ((uint32_t*)(ws + OFF_AB))[i] = f2bf(w0) | (f2bf(w1) << 16);
  }
  if (c == 0) {
    float sa, sb;
    if (d < 64)        { float inv = gq[d] / sqrtf(vq[d] + EPSV); sa = inv; sb = bq[d] - mq[d] * inv; }
    else if (d < 128)  { sa = 1.0f; sb = 0.0f; }
    else               { int j = d - 128; float inv = gv[j] / sqrtf(vv[j] + EPSV); sa = inv; sb = bv[j] - mv[j] * inv; }
    ws[OFF_BNA + d] = sa;
    ws[OFF_BNB + d] = sb;
  }
  if (i < 8192) {
    int chunk = i >> 8, rem = i & 255, lane = rem >> 2, dp = rem & 3;
    int quad = lane >> 4, k = lane & 15;
    int u = chunk >> 3, t = chunk & 7;
    int dh = 2 * t + (quad >> 1);
    int dwb = (quad & 1) * 8 + dp * 2;
    float w0 = (dh < 15 && dwb     < 15) ? pos_w[k * 900 + u * 225 + dh * 15 + dwb]     : 0.0f;
    float w1 = (dh < 15 && dwb + 1 < 15) ? pos_w[k * 900 + u * 225 + dh * 15 + dwb + 1] : 0.0f;
    ((uint32_t*)(ws + OFF_WT))[i] = f2bf(w0) | (f2bf(w1) << 16);
  }
  if (i < 1024) ws[OFF_KS + i] = 0.0f;
}

// ---------------- stage 1: QKV projection via MFMA 32x32x16 bf16 --------------
__launch_bounds__(256, 2)
__global__ void qkv_mfma(const float* __restrict__ x, const float* __restrict__ wsc,
                         float* __restrict__ Y) {
  __shared__ uint32_t X[64 * 128];   // 32 KB
  __shared__ float BNs[768];
  int tid = threadIdx.x;
  int n0 = blockIdx.x * 64, b = blockIdx.y;
  for (int i = tid; i < 768; i += 256) BNs[i] = wsc[OFF_BNA + i];
  const size_t xb = (size_t)b * NC * NPIX;
#pragma unroll
  for (int it = 0; it < 4; ++it) {
    int n2 = tid & 31;
    int cp4 = it * 8 + (tid >> 5);
    const float* xp = x + xb + (size_t)(cp4 * 8) * NPIX + n0 + n2 * 2;
    float2 ld[8];
#pragma unroll
    for (int j = 0; j < 8; ++j) ld[j] = *(const float2*)(xp + (size_t)j * NPIX);
    uint32_t e0, e1, e2, e3, o0, o1, o2, o3;
    e0 = f2bf(ld[0].x) | (f2bf(ld[1].x) << 16);
    e1 = f2bf(ld[2].x) | (f2bf(ld[3].x) << 16);
    e2 = f2bf(ld[4].x) | (f2bf(ld[5].x) << 16);
    e3 = f2bf(ld[6].x) | (f2bf(ld[7].x) << 16);
    o0 = f2bf(ld[0].y) | (f2bf(ld[1].y) << 16);
    o1 = f2bf(ld[2].y) | (f2bf(ld[3].y) << 16);
    o2 = f2bf(ld[4].y) | (f2bf(ld[5].y) << 16);
    o3 = f2bf(ld[6].y) | (f2bf(ld[7].y) << 16);
    int ne = 2 * n2, no = ne + 1;
    uint4 ve; ve.x = e0; ve.y = e1; ve.z = e2; ve.w = e3;
    uint4 vo; vo.x = o0; vo.y = o1; vo.z = o2; vo.w = o3;
    *(uint4*)(X + ne * 128 + ((cp4 ^ (ne & 31)) << 2)) = ve;
    *(uint4*)(X + no * 128 + ((cp4 ^ (no & 31)) << 2)) = vo;
  }
  __syncthreads();
  int lane = tid & 63, w = tid >> 6;
  int n31 = lane & 31, h5 = lane >> 5;
  f32x16 acc[3][2];
#pragma unroll
  for (int dt = 0; dt < 3; ++dt)
#pragma unroll
    for (int nt = 0; nt < 2; ++nt)
#pragma unroll
      for (int e = 0; e < 16; ++e) acc[dt][nt][e] = 0.0f;
  const uint4* AB = (const uint4*)(wsc + OFF_AB);
#pragma unroll 4
  for (int kc = 0; kc < 16; ++kc) {
    bf16x8 af[3];
#pragma unroll
    for (int dt = 0; dt < 3; ++dt) {
      union { uint4 q; bf16x8 v; } tmp;
      tmp.q = AB[(size_t)(((w * 3 + dt) * 16 + kc)) * 64 + lane];
      af[dt] = tmp.v;
    }
#pragma unroll
    for (int nt = 0; nt < 2; ++nt) {
      union { uint4 q; bf16x8 v; } bu;
      bu.q = *(const uint4*)(X + (nt * 32 + n31) * 128 + (((2 * kc + h5) ^ n31) << 2));
#pragma unroll
      for (int dt = 0; dt < 3; ++dt)
        acc[dt][nt] = __builtin_amdgcn_mfma_f32_32x32x16_bf16(af[dt], bu.v, acc[dt][nt], 0, 0, 0);
    }
  }
#pragma unroll
  for (int dt = 0; dt < 3; ++dt) {
    int dgt = w * 3 + dt;
    float sa[16], sb[16];
#pragma unroll
    for (int g = 0; g < 4; ++g) {
      *(float4*)(sa + g * 4) = *(const float4*)(BNs + dgt * 32 + g * 8 + h5 * 4);
      *(float4*)(sb + g * 4) = *(const float4*)(BNs + 384 + dgt * 32 + g * 8 + h5 * 4);
    }
#pragma unroll
    for (int nt = 0; nt < 2; ++nt) {
      int pix = n0 + nt * 32 + n31;
      if (dgt < 2) {
        uint2* qb2 = (uint2*)(Y + (size_t)b * 384 * NPIX);
#pragma unroll
        for (int g = 0; g < 4; ++g) {
          float y0 = fmaf(acc[dt][nt][4 * g + 0], sa[4 * g + 0], sb[4 * g + 0]);
          float y1 = fmaf(acc[dt][nt][4 * g + 1], sa[4 * g + 1], sb[4 * g + 1]);
          float y2 = fmaf(acc[dt][nt][4 * g + 2], sa[4 * g + 2], sb[4 * g + 2]);
          float y3 = fmaf(acc[dt][nt][4 * g + 3], sa[4 * g + 3], sb[4 * g + 3]);
          uint2 val;
          val.x = f2bf(y0) | (f2bf(y1) << 16);
          val.y = f2bf(y2) | (f2bf(y3) << 16);
          qb2[(size_t)(dgt * 8 + 2 * g + h5) * NPIX + pix] = val;
        }
      } else {
#pragma unroll
        for (int g = 0; g < 4; ++g)
#pragma unroll
          for (int ki = 0; ki < 4; ++ki) {
            int d = dgt * 32 + 8 * g + 4 * h5 + ki;
            Y[((size_t)b * 384 + d) * NPIX + pix] =
                fmaf(acc[dt][nt][4 * g + ki], sa[4 * g + ki], sb[4 * g + ki]);
          }
      }
    }
  }
}

// ---------------- stage 2: Lc partials via MFMA, exp(k) inline ----------------
// grid (16 bx, 4 u, 16 b), 256 thr. Wave slot = bx*4+w (64 slots); chunks
// c = slot + 64i. Block-level LDS reduction -> one 1024-float partial/block.
__launch_bounds__(256)
__global__ void lc_mfma(float* __restrict__ Y, float* __restrict__ ws) {
  __shared__ float R[4096];
  __shared__ float Rs[64];
  int bx = blockIdx.x, u = blockIdx.y, b = blockIdx.z;
  int tid = threadIdx.x;
  int lane = tid & 63, w = tid >> 6;
  int col = lane & 15, quad = lane >> 4;
  int slot = bx * 4 + w;
  const float* krow  = Y + ((size_t)(b * 384 + 64 + u * 16 + col)) * NPIX;
  const float* vbase = Y + ((size_t)(b * 384 + 128 + u * 64 + col)) * NPIX;
  f32x4 acc[4];
#pragma unroll
  for (int vt = 0; vt < 4; ++vt) acc[vt] = (f32x4){0.f, 0.f, 0.f, 0.f};
  float ssum = 0.0f;
  for (int c = slot; c < 98; c += 64) {
    int n0 = c * 32 + quad * 8;
    float4 k0 = *(const float4*)(krow + n0);
    float4 k1 = *(const float4*)(krow + n0 + 4);
    float e0 = __expf(k0.x), e1 = __expf(k0.y), e2 = __expf(k0.z), e3 = __expf(k0.w);
    float e4 = __expf(k1.x), e5 = __expf(k1.y), e6 = __expf(k1.z), e7 = __expf(k1.w);
    ssum += (e0 + e1 + e2 + e3) + (e4 + e5 + e6 + e7);
    union { uint32_t d[4]; bf16x8 v; } kb;
    kb.d[0] = pk_trunc(e0, e1);
    kb.d[1] = pk_trunc(e2, e3);
    kb.d[2] = pk_trunc(e4, e5);
    kb.d[3] = pk_trunc(e6, e7);
#pragma unroll
    for (int vt = 0; vt < 4; ++vt) {
      const float* vp = vbase + (size_t)(vt * 16) * NPIX + n0;
      float4 v0 = *(const float4*)(vp);
      float4 v1 = *(const float4*)(vp + 4);
      union { uint32_t d[4]; bf16x8 v; } vb;
      vb.d[0] = pk_trunc(v0.x, v0.y);
      vb.d[1] = pk_trunc(v0.z, v0.w);
      vb.d[2] = pk_trunc(v1.x, v1.y);
      vb.d[3] = pk_trunc(v1.z, v1.w);
      acc[vt] = __builtin_amdgcn_mfma_f32_16x16x32_bf16(vb.v, kb.v, acc[vt], 0, 0, 0);
    }
  }
  ssum += __shfl_xor(ssum, 16);
  ssum += __shfl_xor(ssum, 32);
#pragma unroll
  for (int vt = 0; vt < 4; ++vt)
#pragma unroll
    for (int r = 0; r < 4; ++r)
      R[w * 1024 + vt * 256 + quad * 64 + r * 16 + col] = acc[vt][r];
  if (lane < 16) Rs[w * 16 + col] = ssum;
  __syncthreads();
  float* P = Y + (size_t)b * 384 * NPIX + 32 * NPIX + (size_t)(u * 16 + bx) * 1024;
  float4 s0 = *(const float4*)(R + tid * 4);
  float4 s1 = *(const float4*)(R + 1024 + tid * 4);
  float4 s2 = *(const float4*)(R + 2048 + tid * 4);
  float4 s3 = *(const float4*)(R + 3072 + tid * 4);
  float4 tot;
  tot.x = (s0.x + s1.x) + (s2.x + s3.x);
  tot.y = (s0.y + s1.y) + (s2.y + s3.y);
  tot.z = (s0.z + s1.z) + (s2.z + s3.z);
  tot.w = (s0.w + s1.w) + (s2.w + s3.w);
  *(float4*)(P + tid * 4) = tot;
  if (tid < 16)
    atomicAdd(&ws[OFF_KS + b * 64 + u * 16 + tid],
              (Rs[tid] + Rs[16 + tid]) + (Rs[32 + tid] + Rs[48 + tid]));
}

// ---------------- stage 3: reduce partials -> Lc (scaled by 1/S) --------------
__global__ void lc_reduce(const float* __restrict__ Y, float* __restrict__ ws) {
  int i = blockIdx.x, b = blockIdx.y;
  int t = threadIdx.x;
  __shared__ float invS[64];
  if (t < 64) invS[t] = 1.0f / ws[OFF_KS + b * 64 + t];
  __syncthreads();
  int idx = i * 256 + t;
  int k = idx & 15, v = idx >> 4;
  const float* P = Y + (size_t)b * 384 * NPIX + 32 * NPIX;
  float tot = 0.0f;
#pragma unroll
  for (int u = 0; u < 4; ++u) {
    float su = 0.0f;
#pragma unroll
    for (int s = 0; s < 16; ++s) su += P[(size_t)(u * 16 + s) * 1024 + idx];
    tot += su * invS[u * 16 + k];
  }
  ws[OFF_LC + (b * 16 + k) * 64 + v] = tot;
}

// ---------------- stage 4: MFMA position conv + fused output contraction ------
#define ROWS   29
#define RSTR2  74
#define UPITCH2 2146   // ROWS * RSTR2
#define LDSW2  8584    // 4 * UPITCH2

__launch_bounds__(512, 4)
__global__ void pos_lambda_mfma(const float* __restrict__ Y, const float* __restrict__ wsc,
                                const float* __restrict__ pos_b, float* __restrict__ out) {
  __shared__ uint32_t S[LDSW2];
  int v = blockIdx.x, b = blockIdx.y, band = blockIdx.z;
  int rb = band * 14;
  int tid = threadIdx.x;
  // ---- stage padded v planes: pair tasks (4u x 29rows x 37pairs = 4292) ----
  const float* vplane = Y + ((size_t)(b * 384 + 128)) * NPIX + v * NPIX;
  for (int ii = tid; ii < 4292; ii += 512) {
    int u = ii / 1073;
    int rem = ii - u * 1073;
    int row = rem / 37;
    int pr = rem - row * 37;
    int gr = rb + row - 7;
    int grc = min(max(gr, 0), NW - 1);
    bool rv = (gr >= 0) && (gr < NW);
    const float* vp = vplane + (size_t)(u * 64) * NPIX + grc * NW;
    int g0 = 2 * pr - 7;
    float e[3];
#pragma unroll
    for (int j = 0; j < 3; ++j) {
      int g = g0 + j;
      int gc = min(max(g, 0), NW - 1);
      float val = vp[gc];
      e[j] = (rv && g >= 0 && g < NW) ? val : 0.0f;
    }
    uint2 dd;
    dd.x = pk_trunc(e[0], e[1]);
    dd.y = pk_trunc(e[1], e[2]);
    *(uint2*)(S + u * UPITCH2 + row * RSTR2 + 2 * pr) = dd;
  }
  __syncthreads();
  int lane = tid & 63, wid = tid >> 6;
  int quad = lane >> 4, n = lane & 15;
  int dhp = quad >> 1;
  int ct = wid & 3, p = wid >> 2;
  int cb = (ct == 3) ? 40 : ct * 16;
  int sb = cb + n + (quad & 1) * 8;
  int abase = (p + dhp) * RSTR2 + sb;
  const uint4* wt = (const uint4*)(wsc + OFF_WT);
  f32x4 acc[7];
#pragma unroll
  for (int q = 0; q < 7; ++q) acc[q] = (f32x4){0.f, 0.f, 0.f, 0.f};
#pragma unroll 1
  for (int u = 0; u < 4; ++u) {
    bf16x8 wf[8];
#pragma unroll
    for (int t = 0; t < 8; ++t) {
      union { uint4 q; bf16x8 v; } tmp;
      tmp.q = wt[(u * 8 + t) * 64 + lane];
      wf[t] = tmp.v;
    }
    int au = u * UPITCH2 + abase;
#pragma unroll
    for (int PP = 0; PP < 14; ++PP) {
      int a = au + PP * (2 * RSTR2);
      union { uint32_t u4[4]; bf16x8 v8; } bu;
      bu.u4[0] = S[a];     bu.u4[1] = S[a + 2];
      bu.u4[2] = S[a + 4]; bu.u4[3] = S[a + 6];
#pragma unroll
      for (int t = 0; t < 8; ++t) {
        int q = PP - t;
        if (q >= 0 && q < 7)
          acc[q] = __builtin_amdgcn_mfma_f32_16x16x32_bf16(wf[t], bu.v8, acc[q], 0, 0, 0);
      }
    }
  }
  float lcq[4];
#pragma unroll
  for (int r = 0; r < 4; ++r) {
    int k = quad * 4 + r;
    lcq[r] = wsc[OFF_LC + (b * 16 + k) * 64 + v] + pos_b[k];
  }
  const uint2* qb2 = (const uint2*)(Y + (size_t)b * 384 * NPIX);
#pragma unroll
  for (int q = 0; q < 7; ++q) {
    int rr = rb + p + 2 * q;
    int pix = rr * NW + cb + n;
    float m0 = acc[q][0] + lcq[0], m1 = acc[q][1] + lcq[1];
    float m2 = acc[q][2] + lcq[2], m3 = acc[q][3] + lcq[3];
    float pp[4];
#pragma unroll
    for (int j = 0; j < 4; ++j) {
      int h = quad ^ j;
      uint2 qd = qb2[(h * 4 + quad) * NPIX + pix];
      float q0 = __uint_as_float(qd.x << 16);
      float q1 = __uint_as_float(qd.x & 0xffff0000u);
      float q2 = __uint_as_float(qd.y << 16);
      float q3 = __uint_as_float(qd.y & 0xffff0000u);
      pp[j] = fmaf(q0, m0, fmaf(q1, m1, fmaf(q2, m2, q3 * m3)));
    }
    float t0 = pp[0] + __shfl_xor(pp[1], 16);
    float t2 = pp[2] + __shfl_xor(pp[3], 16);
    float y  = t0 + __shfl_xor(t2, 32);
    out[((size_t)(b * 256 + quad * 64 + v)) * NPIX + pix] = y;
  }
}

extern "C" void kernel_launch(void* const* d_in, const int* in_sizes, int n_in,
                              void* d_out, int out_size, void* d_ws, size_t ws_size,
                              hipStream_t stream) {
  const float* x     = (const float*)d_in[0];
  const float* Wq    = (const float*)d_in[1];
  const float* Wk    = (const float*)d_in[2];
  const float* Wv    = (const float*)d_in[3];
  const float* pos_w = (const float*)d_in[4];
  const float* pos_b = (const float*)d_in[5];
  const float* gq    = (const float*)d_in[6];
  const float* bq    = (const float*)d_in[7];
  const float* mq    = (const float*)d_in[8];
  const float* vq    = (const float*)d_in[9];
  const float* gv    = (const float*)d_in[10];
  const float* bv    = (const float*)d_in[11];
  const float* mv    = (const float*)d_in[12];
  const float* vv    = (const float*)d_in[13];
  float* ws  = (float*)d_ws;
  float* out = (float*)d_out;
  float* Y   = ws + OFF_Y;

  prep_kernel<<<dim3(384), 256, 0, stream>>>(Wq, Wk, Wv, pos_w, gq, bq, mq, vq,
                                             gv, bv, mv, vv, ws);
  qkv_mfma<<<dim3(49, 16), 256, 0, stream>>>(x, ws, Y);
  lc_mfma<<<dim3(16, 4, 16), 256, 0, stream>>>(Y, ws);
  lc_reduce<<<dim3(4, 16), 256, 0, stream>>>(Y, ws);
  pos_lambda_mfma<<<dim3(64, 16, 4), 512, 0, stream>>>(Y, ws, pos_b, out);
}